// Round 9
// baseline (491.665 us; speedup 1.0000x reference)
//
#include <hip/hip_runtime.h>

#define N_PTS 131072
#define TILE 128
#define THREADS 1024

typedef __bf16 bf16;
typedef __bf16 bf16x8 __attribute__((ext_vector_type(8)));
typedef float f32x4 __attribute__((ext_vector_type(4)));

// ---------------- workspace layout (bytes) ----------------
#define WS_PERM_OFF   256                       // int perm[N_PTS]
#define WS_WPACK_OFF  (256 + N_PTS * 4)         // = 524544, bf16 packed weights
// packed-weight element offsets (bf16 elements, all [out][K] "transposed")
#define OFF_W0     0          // [256][64]   (k=63 zero pad)
#define OFF_WS     16384      // [3][256][256]
#define OFF_TW0    212992     // [4][256][320] (k: 0..62 pts, 63 zero, 64..319 h)
#define OFF_TWS    540672     // [12][256][256]
#define OFF_FEATW  1327104    // [4][256][256]
#define OFF_VIEWSW 1589248    // [4][128][288] (k: 0..255 feat, 256..282 views, 283..287 zero)
#define TOTAL_PACK 1736704

// ---------------- LDS layout (bytes) ----------------
// PTS [128][64]bf16 (16KB) + in-place H [128][256]bf16 (64KB)
// + B ring-3 x 16KB (48KB) = 128KB -> 1 block/CU, 16 waves (4/SIMD).
#define PTS_BASE 0
#define H_BASE   16384
#define B_BASE   81920
#define LDS_BYTES 131072

__device__ __forceinline__ unsigned swz(unsigned base, unsigned row, unsigned rowstride,
                                        unsigned kbyte) {
  return (base + row * rowstride + kbyte) ^ ((row & 7u) << 4);
}

// async global->LDS, 16B per lane; LDS dest = wave-uniform base + lane*16
__device__ __forceinline__ void gload_lds16(const bf16* g, char* l) {
  __builtin_amdgcn_global_load_lds(
      (const __attribute__((address_space(1))) void*)g,
      (__attribute__((address_space(3))) void*)l, 16, 0, 0);
}

// ================= weight pack (fp32->bf16 transpose) + head count =================
__global__ void k_pack(const float* __restrict__ W0, const float* __restrict__ Ws,
                       const float* __restrict__ tW0, const float* __restrict__ tWs,
                       const float* __restrict__ featW, const float* __restrict__ viewsW,
                       bf16* __restrict__ out, const int* __restrict__ head,
                       int* __restrict__ ctrl) {
  __shared__ int lc[4];
  if (threadIdx.x < 4) lc[threadIdx.x] = 0;
  __syncthreads();
  int gid = blockIdx.x * blockDim.x + threadIdx.x;
  if (gid < N_PTS) atomicAdd(&lc[head[gid]], 1);

  for (int idx = gid; idx < TOTAL_PACK; idx += gridDim.x * blockDim.x) {
    float v;
    if (idx < OFF_WS) {
      int o = idx >> 6, k = idx & 63;
      v = (k < 63) ? W0[k * 256 + o] : 0.f;
    } else if (idx < OFF_TW0) {
      int i = idx - OFF_WS; int l = i >> 16, r = i & 65535, o = r >> 8, k = r & 255;
      v = Ws[l * 65536 + k * 256 + o];
    } else if (idx < OFF_TWS) {
      int i = idx - OFF_TW0; int h = i / 81920, r = i % 81920, o = r / 320, k = r % 320;
      v = (k < 63) ? tW0[(h * 319 + k) * 256 + o]
                   : (k == 63 ? 0.f : tW0[(h * 319 + k - 1) * 256 + o]);
    } else if (idx < OFF_FEATW) {
      int i = idx - OFF_TWS; int hj = i >> 16, r = i & 65535, o = r >> 8, k = r & 255;
      v = tWs[(hj * 256 + k) * 256 + o];
    } else if (idx < OFF_VIEWSW) {
      int i = idx - OFF_FEATW; int h = i >> 16, r = i & 65535, o = r >> 8, k = r & 255;
      v = featW[(h * 256 + k) * 256 + o];
    } else {
      int i = idx - OFF_VIEWSW; int h = i / 36864, r = i % 36864, o = r / 288, k = r % 288;
      v = (k < 283) ? viewsW[(h * 283 + k) * 128 + o] : 0.f;
    }
    out[idx] = (bf16)v;
  }
  __syncthreads();
  if (threadIdx.x < 4 && lc[threadIdx.x]) atomicAdd(&ctrl[threadIdx.x], lc[threadIdx.x]);
}

// ================= bucketing =================
// ctrl ints: [0..3]=counts [8..12]=offsets [16..19]=cursor [24..28]=tile_base
__global__ void k_scan(int* c) {
  c[8] = 0; c[24] = 0;
  for (int h = 0; h < 4; ++h) {
    c[8 + h + 1] = c[8 + h] + c[h];
    c[16 + h] = c[8 + h];
    c[24 + h + 1] = c[24 + h] + (c[h] + TILE - 1) / TILE;
  }
}

__global__ void k_scatter(const int* __restrict__ head, int* __restrict__ c,
                          int* __restrict__ perm) {
  int p = blockIdx.x * 256 + threadIdx.x;
  int h = (p < N_PTS) ? head[p] : -1;
  int lane = threadIdx.x & 63;
  #pragma unroll
  for (int hh = 0; hh < 4; ++hh) {
    unsigned long long m = __ballot(h == hh);
    if (m == 0ull) continue;
    int leader = __builtin_ctzll(m);
    int base = 0;
    if (lane == leader) base = atomicAdd(&c[16 + hh], __popcll(m));
    base = __shfl(base, leader);
    if (h == hh) {
      int rank = __popcll(m & ((1ull << lane) - 1ull));
      perm[base + rank] = p;
    }
  }
}

// ================= B tile staging (global_load_lds) =================
// Tile = B[o][kk..kk+32), o in [0,OUTS). 16 waves x 1KB regions (8 for
// OUTS=128). LDS slot (o,j) at byte o*64+j*16 holds global k-chunk
// (j ^ (o&3)): source-side XOR swizzle (LDS dest stays linear for
// global_load_lds) -> reader's ds_read is 2-way max.
template <int OUTS>
__device__ __forceinline__ void stage_B(const bf16* __restrict__ Wt, int wK, int kk,
                                        char* lds, int bufsel, int wave, int lane) {
  if (OUTS == 256 || wave < 8) {
    int o = wave * 16 + (lane >> 2);
    int j = lane & 3;
    const bf16* g = Wt + o * wK + kk + ((j ^ (o & 3)) << 3);
    gload_lds16(g, lds + B_BASE + bufsel * 16384 + wave * 1024);
  }
}

// ================= fused MLP layer (MFMA, counted-vmcnt ring-3 B) =================
// T3/T4 port: raw s_barrier + per-wave counted vmcnt. Each wave waits only
// its OWN stage loads (vmcnt(1) leaves stage(kc+1) in flight); after the
// barrier, every wave's stage(kc) has landed -> buf[kc%3] complete. Ring-3
// lets stage run 2 tiles ahead; overwrite of buf[(kc+2)%3] is safe because
// its readers (kc-1) completed their ds_reads before their MFMAs, hence
// before this kc's barrier. Extra in-flight loads (hoisted bias etc.) only
// make vmcnt(N) over-wait, never under-wait.
template <int NFRAG, bool RELU, int A0KC, int A1KC, int OUTS>
__device__ __forceinline__ void mfma_layer(char* lds, const bf16* __restrict__ Wt, int wK,
                                           const float* __restrict__ bias,
                                           int a0_base, int a0_stride,
                                           int a1_base, int a1_stride,
                                           int out_base, int out_stride,
                                           int lane, int wave) {
  const int l15 = lane & 15, l4 = lane >> 4;
  const int wc = wave & 7, wr = wave >> 3;
  constexpr int KC = A0KC + A1KC;
  f32x4 acc[4][NFRAG];
  #pragma unroll
  for (int m = 0; m < 4; ++m)
    #pragma unroll
    for (int n = 0; n < NFRAG; ++n) acc[m][n] = (f32x4){0.f, 0.f, 0.f, 0.f};

  const int c0 = wc * (NFRAG * 16);

  // prologue: stage 2 tiles ahead
  stage_B<OUTS>(Wt, wK, 0, lds, 0, wave, lane);
  if (KC > 1) stage_B<OUTS>(Wt, wK, 32, lds, 1, wave, lane);

  #pragma unroll 1
  for (int kc = 0; kc < KC; ++kc) {
    // counted drain: stage(kc) done, stage(kc+1) stays in flight
    if (kc < KC - 1) asm volatile("s_waitcnt vmcnt(1)" ::: "memory");
    else             asm volatile("s_waitcnt vmcnt(0)" ::: "memory");
    __builtin_amdgcn_s_barrier();

    const int buf = kc % 3;
    if (kc + 2 < KC) stage_B<OUTS>(Wt, wK, (kc + 2) * 32, lds, (kc + 2) % 3, wave, lane);

    const int base   = (kc < A0KC) ? a0_base   : a1_base;
    const int stride = (kc < A0KC) ? a0_stride : a1_stride;
    const int kl     = ((kc < A0KC) ? kc : kc - A0KC) * 32;
    bf16x8 a[4];
    #pragma unroll
    for (int m = 0; m < 4; ++m)
      a[m] = *(const bf16x8*)(lds + swz(base, wr * 64 + m * 16 + l15, stride,
                                        (kl + l4 * 8) * 2));
    bf16x8 b[NFRAG];
    #pragma unroll
    for (int n = 0; n < NFRAG; ++n) {
      int col = c0 + n * 16 + l15;
      b[n] = *(const bf16x8*)(lds + B_BASE + buf * 16384 + col * 64 + ((l4 ^ (col & 3)) << 4));
    }

    #pragma unroll
    for (int n = 0; n < NFRAG; ++n)
      #pragma unroll
      for (int m = 0; m < 4; ++m)
        acc[m][n] = __builtin_amdgcn_mfma_f32_16x16x32_bf16(a[m], b[n], acc[m][n], 0, 0, 0);
  }

  // epilogue: all A reads done (last kc fully drained) -> in-place safe
  #pragma unroll
  for (int n = 0; n < NFRAG; ++n) {
    int col = c0 + n * 16 + l15;
    float bv = bias[col];
    #pragma unroll
    for (int m = 0; m < 4; ++m) {
      #pragma unroll
      for (int j = 0; j < 4; ++j) {
        float v = acc[m][n][j] + bv;
        if (RELU) v = fmaxf(v, 0.f);
        int row = wr * 64 + m * 16 + l4 * 4 + j;
        *(bf16*)(lds + swz(out_base, row, out_stride, col * 2)) = (bf16)v;
      }
    }
  }
  __syncthreads();  // epilogue visible; all counters drained
}

// ================= main fused kernel =================
// 16 waves = 2 row-halves x 8 col-groups; each wave 64 rows x NFRAG*16 cols.
__global__ __launch_bounds__(THREADS, 4) void k_main(
    const float* __restrict__ x, const int* __restrict__ ctrl, const int* __restrict__ perm,
    const bf16* __restrict__ wpack,
    const float* __restrict__ b0, const float* __restrict__ bs,
    const float* __restrict__ tb0p, const float* __restrict__ tbsp,
    const float* __restrict__ featb, const float* __restrict__ alphaW,
    const float* __restrict__ alphab, const float* __restrict__ viewsb,
    const float* __restrict__ rgbW, const float* __restrict__ rgbb,
    float* __restrict__ outp) {
  __shared__ __attribute__((aligned(16))) char lds[LDS_BYTES];
  __shared__ int pidx[TILE];
  __shared__ float alpha_s[TILE];

  const int tid = threadIdx.x;
  const int lane = tid & 63, wave = tid >> 6;

  // ---- resolve head + tile from control block ----
  const int tbA = ctrl[24], tbB = ctrl[25], tbC = ctrl[26], tbD = ctrl[27], tbE = ctrl[28];
  const int bid = blockIdx.x;
  if (bid >= tbE) return;
  const int hh = (bid >= tbB) + (bid >= tbC) + (bid >= tbD);
  const int tb_h = (hh == 0) ? tbA : ((hh == 1) ? tbB : ((hh == 2) ? tbC : tbD));
  const int start = ctrl[8 + hh] + (bid - tb_h) * TILE;
  const int nv = min(TILE, ctrl[8 + hh + 1] - start);

  if (tid < TILE) pidx[tid] = (tid < nv) ? perm[start + tid] : -1;
  __syncthreads();

  // ---- pts -> LDS bf16 [128][64] (col 63 = 0, rows>=nv = 0) ----
  for (int i = tid; i < TILE * 64; i += THREADS) {
    int row = i >> 6, c = i & 63;
    int p = pidx[row];
    float v = (p >= 0 && c < 63) ? x[p * 90 + c] : 0.f;
    *(bf16*)(lds + swz(PTS_BASE, row, 128, c * 2)) = (bf16)v;
  }
  __syncthreads();

  const bf16* W0p    = wpack + OFF_W0;
  const bf16* Wsp    = wpack + OFF_WS;
  const bf16* tW0p   = wpack + OFF_TW0 + hh * 81920;
  const bf16* tWsp   = wpack + OFF_TWS + hh * 3 * 65536;
  const bf16* featWp = wpack + OFF_FEATW + hh * 65536;
  const bf16* viewsWp= wpack + OFF_VIEWSW + hh * 36864;

  // trunk: 63->256, 3x 256->256 (in-place H)
  mfma_layer<2, true, 2, 0, 256>(lds, W0p, 64, b0, PTS_BASE, 128, 0, 0, H_BASE, 512, lane, wave);
  mfma_layer<2, true, 8, 0, 256>(lds, Wsp,          256, bs,       H_BASE, 512, 0, 0, H_BASE, 512, lane, wave);
  mfma_layer<2, true, 8, 0, 256>(lds, Wsp + 65536,  256, bs + 256, H_BASE, 512, 0, 0, H_BASE, 512, lane, wave);
  mfma_layer<2, true, 8, 0, 256>(lds, Wsp + 131072, 256, bs + 512, H_BASE, 512, 0, 0, H_BASE, 512, lane, wave);
  // T0: concat(pts, h) 320 -> 256
  mfma_layer<2, true, 2, 8, 256>(lds, tW0p, 320, tb0p + hh * 256,
                                 PTS_BASE, 128, H_BASE, 512, H_BASE, 512, lane, wave);

  // views -> PTS cols 0..31 (T0's PTS reads complete; next reader is the
  // views layer, many barriers later)
  for (int i = tid; i < TILE * 32; i += THREADS) {
    int row = i >> 5, c = i & 31;
    int p = pidx[row];
    float v = (p >= 0 && c < 27) ? x[p * 90 + 63 + c] : 0.f;
    *(bf16*)(lds + swz(PTS_BASE, row, 128, c * 2)) = (bf16)v;
  }

  // head layers
  mfma_layer<2, true, 8, 0, 256>(lds, tWsp,          256, tbsp + hh * 768,       H_BASE, 512, 0, 0, H_BASE, 512, lane, wave);
  mfma_layer<2, true, 8, 0, 256>(lds, tWsp + 65536,  256, tbsp + hh * 768 + 256, H_BASE, 512, 0, 0, H_BASE, 512, lane, wave);
  mfma_layer<2, true, 8, 0, 256>(lds, tWsp + 131072, 256, tbsp + hh * 768 + 512, H_BASE, 512, 0, 0, H_BASE, 512, lane, wave);

  // ---- alpha = ha . alphaW[hh] + alphab (waves 0-7; feat's epilogue can't
  //      overwrite H until all waves pass feat's kc barriers, which happens
  //      after these waves finish alpha) ----
  if (wave < 8) {
    int p = wave * 16 + (lane & 15);
    int kq = lane >> 4;
    const float* aW = alphaW + hh * 256;
    float s = 0.f;
    for (int i = 0; i < 8; ++i) {
      int k = kq * 64 + i * 8;
      bf16x8 hv8 = *(const bf16x8*)(lds + swz(H_BASE, p, 512, k * 2));
      #pragma unroll
      for (int j = 0; j < 8; ++j) s += (float)hv8[j] * aW[k + j];
    }
    s += __shfl_xor(s, 16);
    s += __shfl_xor(s, 32);
    if (kq == 0) alpha_s[p] = s + alphab[hh];
  }

  // feat: 256->256 in-place, NO relu
  mfma_layer<2, false, 8, 0, 256>(lds, featWp, 256, featb + hh * 256,
                                  H_BASE, 512, 0, 0, H_BASE, 512, lane, wave);
  // views: concat(feat, views[32pad]) 288 -> 128, relu, into H cols 0..127
  mfma_layer<1, true, 8, 1, 128>(lds, viewsWp, 288, viewsb + hh * 128,
                                 H_BASE, 512, PTS_BASE, 128, H_BASE, 512, lane, wave);

  // ---- rgb = hv . rgbW[hh] + rgbb ; write float4 {r,g,b,alpha} (waves 0-7) ----
  if (wave < 8) {
    int p = wave * 16 + (lane & 15);
    int kq = lane >> 4;
    const float* rW = rgbW + hh * 128 * 3;
    float r0 = 0.f, r1 = 0.f, r2 = 0.f;
    for (int i = 0; i < 4; ++i) {
      int k = kq * 32 + i * 8;
      bf16x8 hv8 = *(const bf16x8*)(lds + swz(H_BASE, p, 512, k * 2));
      #pragma unroll
      for (int j = 0; j < 8; ++j) {
        float hvf = (float)hv8[j];
        r0 += hvf * rW[(k + j) * 3 + 0];
        r1 += hvf * rW[(k + j) * 3 + 1];
        r2 += hvf * rW[(k + j) * 3 + 2];
      }
    }
    r0 += __shfl_xor(r0, 16); r0 += __shfl_xor(r0, 32);
    r1 += __shfl_xor(r1, 16); r1 += __shfl_xor(r1, 32);
    r2 += __shfl_xor(r2, 16); r2 += __shfl_xor(r2, 32);
    if (kq == 0 && p < nv) {
      int pt = pidx[p];
      float4 o = make_float4(r0 + rgbb[hh * 3 + 0], r1 + rgbb[hh * 3 + 1],
                             r2 + rgbb[hh * 3 + 2], alpha_s[p]);
      *(float4*)(outp + pt * 4) = o;
    }
  }
}

// ================= launch =================
extern "C" void kernel_launch(void* const* d_in, const int* in_sizes, int n_in,
                              void* d_out, int out_size, void* d_ws, size_t ws_size,
                              hipStream_t stream) {
  const float* x      = (const float*)d_in[0];
  const int*   head   = (const int*)d_in[1];
  const float* W0     = (const float*)d_in[2];
  const float* b0     = (const float*)d_in[3];
  const float* Ws     = (const float*)d_in[4];
  const float* bs     = (const float*)d_in[5];
  const float* tW0    = (const float*)d_in[6];
  const float* tb0    = (const float*)d_in[7];
  const float* tWs    = (const float*)d_in[8];
  const float* tbs    = (const float*)d_in[9];
  const float* featW  = (const float*)d_in[10];
  const float* featb  = (const float*)d_in[11];
  const float* alphaW = (const float*)d_in[12];
  const float* alphab = (const float*)d_in[13];
  const float* viewsW = (const float*)d_in[14];
  const float* viewsb = (const float*)d_in[15];
  const float* rgbW   = (const float*)d_in[16];
  const float* rgbb   = (const float*)d_in[17];

  int*  ctrl  = (int*)d_ws;
  int*  perm  = (int*)((char*)d_ws + WS_PERM_OFF);
  bf16* wpack = (bf16*)((char*)d_ws + WS_WPACK_OFF);

  hipMemsetAsync(ctrl, 0, 256, stream);
  k_pack<<<2048, 256, 0, stream>>>(W0, Ws, tW0, tWs, featW, viewsW, wpack, head, ctrl);
  k_scan<<<1, 1, 0, stream>>>(ctrl);
  k_scatter<<<N_PTS / 256, 256, 0, stream>>>(head, ctrl, perm);
  k_main<<<N_PTS / TILE + 4, THREADS, 0, stream>>>(x, ctrl, perm, wpack,
                                                   b0, bs, tb0, tbs, featb, alphaW, alphab,
                                                   viewsb, rgbW, rgbb, (float*)d_out);
}

// Round 10
// 489.932 us; speedup vs baseline: 1.0035x; 1.0035x over previous
//
#include <hip/hip_runtime.h>

#define N_PTS 131072
#define TILE 128
#define THREADS 1024

typedef __bf16 bf16;
typedef __bf16 bf16x8 __attribute__((ext_vector_type(8)));
typedef float f32x4 __attribute__((ext_vector_type(4)));

// ---------------- workspace layout (bytes) ----------------
#define WS_PERM_OFF   256                       // int perm[N_PTS]
#define WS_WPACK_OFF  (256 + N_PTS * 4)         // = 524544, bf16 packed weights
// packed-weight element offsets (bf16 elements, all [out][K] "transposed")
#define OFF_W0     0          // [256][64]   (k=63 zero pad)
#define OFF_WS     16384      // [3][256][256]
#define OFF_TW0    212992     // [4][256][320] (k: 0..62 pts, 63 zero, 64..319 h)
#define OFF_TWS    540672     // [12][256][256]
#define OFF_FEATW  1327104    // [4][256][256]
#define OFF_VIEWSW 1589248    // [4][128][288] (k: 0..255 feat, 256..282 views, 283..287 zero)
#define TOTAL_PACK 1736704

// ---------------- LDS layout (bytes) ----------------
// PTS [128][64]bf16 (16KB) + in-place H [128][256]bf16 (64KB)
// + B ring-3 x 16KB (48KB) = 128KB -> 1 block/CU, 16 waves (4/SIMD).
#define PTS_BASE 0
#define H_BASE   16384
#define B_BASE   81920
#define LDS_BYTES 131072

__device__ __forceinline__ unsigned swz(unsigned base, unsigned row, unsigned rowstride,
                                        unsigned kbyte) {
  return (base + row * rowstride + kbyte) ^ ((row & 7u) << 4);
}

// async global->LDS, 16B per lane; LDS dest = wave-uniform base + lane*16
__device__ __forceinline__ void gload_lds16(const bf16* g, char* l) {
  __builtin_amdgcn_global_load_lds(
      (const __attribute__((address_space(1))) void*)g,
      (__attribute__((address_space(3))) void*)l, 16, 0, 0);
}

// ================= weight pack (fp32->bf16 transpose) + head count =================
__global__ void k_pack(const float* __restrict__ W0, const float* __restrict__ Ws,
                       const float* __restrict__ tW0, const float* __restrict__ tWs,
                       const float* __restrict__ featW, const float* __restrict__ viewsW,
                       bf16* __restrict__ out, const int* __restrict__ head,
                       int* __restrict__ ctrl) {
  __shared__ int lc[4];
  if (threadIdx.x < 4) lc[threadIdx.x] = 0;
  __syncthreads();
  int gid = blockIdx.x * blockDim.x + threadIdx.x;
  if (gid < N_PTS) atomicAdd(&lc[head[gid]], 1);

  for (int idx = gid; idx < TOTAL_PACK; idx += gridDim.x * blockDim.x) {
    float v;
    if (idx < OFF_WS) {
      int o = idx >> 6, k = idx & 63;
      v = (k < 63) ? W0[k * 256 + o] : 0.f;
    } else if (idx < OFF_TW0) {
      int i = idx - OFF_WS; int l = i >> 16, r = i & 65535, o = r >> 8, k = r & 255;
      v = Ws[l * 65536 + k * 256 + o];
    } else if (idx < OFF_TWS) {
      int i = idx - OFF_TW0; int h = i / 81920, r = i % 81920, o = r / 320, k = r % 320;
      v = (k < 63) ? tW0[(h * 319 + k) * 256 + o]
                   : (k == 63 ? 0.f : tW0[(h * 319 + k - 1) * 256 + o]);
    } else if (idx < OFF_FEATW) {
      int i = idx - OFF_TWS; int hj = i >> 16, r = i & 65535, o = r >> 8, k = r & 255;
      v = tWs[(hj * 256 + k) * 256 + o];
    } else if (idx < OFF_VIEWSW) {
      int i = idx - OFF_FEATW; int h = i >> 16, r = i & 65535, o = r >> 8, k = r & 255;
      v = featW[(h * 256 + k) * 256 + o];
    } else {
      int i = idx - OFF_VIEWSW; int h = i / 36864, r = i % 36864, o = r / 288, k = r % 288;
      v = (k < 283) ? viewsW[(h * 283 + k) * 128 + o] : 0.f;
    }
    out[idx] = (bf16)v;
  }
  __syncthreads();
  if (threadIdx.x < 4 && lc[threadIdx.x]) atomicAdd(&ctrl[threadIdx.x], lc[threadIdx.x]);
}

// ================= bucketing =================
// ctrl ints: [0..3]=counts [8..12]=offsets [16..19]=cursor [24..28]=tile_base
__global__ void k_scan(int* c) {
  c[8] = 0; c[24] = 0;
  for (int h = 0; h < 4; ++h) {
    c[8 + h + 1] = c[8 + h] + c[h];
    c[16 + h] = c[8 + h];
    c[24 + h + 1] = c[24 + h] + (c[h] + TILE - 1) / TILE;
  }
}

__global__ void k_scatter(const int* __restrict__ head, int* __restrict__ c,
                          int* __restrict__ perm) {
  int p = blockIdx.x * 256 + threadIdx.x;
  int h = (p < N_PTS) ? head[p] : -1;
  int lane = threadIdx.x & 63;
  #pragma unroll
  for (int hh = 0; hh < 4; ++hh) {
    unsigned long long m = __ballot(h == hh);
    if (m == 0ull) continue;
    int leader = __builtin_ctzll(m);
    int base = 0;
    if (lane == leader) base = atomicAdd(&c[16 + hh], __popcll(m));
    base = __shfl(base, leader);
    if (h == hh) {
      int rank = __popcll(m & ((1ull << lane) - 1ull));
      perm[base + rank] = p;
    }
  }
}

// ================= B tile staging (global_load_lds) =================
// Tile = B[o][kk..kk+32), o in [0,OUTS). 16 waves x 1KB regions (8 for
// OUTS=128). LDS slot (o,j) at byte o*64+j*16 holds global k-chunk
// (j ^ (o&3)): source-side XOR swizzle (LDS dest stays linear for
// global_load_lds) -> reader's ds_read is 2-way max.
template <int OUTS>
__device__ __forceinline__ void stage_B(const bf16* __restrict__ Wt, int wK, int kk,
                                        char* lds, int bufsel, int wave, int lane) {
  if (OUTS == 256 || wave < 8) {
    int o = wave * 16 + (lane >> 2);
    int j = lane & 3;
    const bf16* g = Wt + o * wK + kk + ((j ^ (o & 3)) << 3);
    gload_lds16(g, lds + B_BASE + bufsel * 16384 + wave * 1024);
  }
}

// ================= fused MLP layer (MFMA, counted-vmcnt ring-3 B) =================
// T3/T4 port: raw s_barrier + per-wave counted vmcnt. Each wave waits only
// its OWN stage loads (vmcnt(1) leaves stage(kc+1) in flight); after the
// barrier, every wave's stage(kc) has landed -> buf[kc%3] complete. Ring-3
// lets stage run 2 tiles ahead; overwrite of buf[(kc+2)%3] is safe because
// its readers (kc-1) completed their ds_reads before their MFMAs, hence
// before this kc's barrier. Extra in-flight loads (hoisted bias etc.) only
// make vmcnt(N) over-wait, never under-wait.
template <int NFRAG, bool RELU, int A0KC, int A1KC, int OUTS>
__device__ __forceinline__ void mfma_layer(char* lds, const bf16* __restrict__ Wt, int wK,
                                           const float* __restrict__ bias,
                                           int a0_base, int a0_stride,
                                           int a1_base, int a1_stride,
                                           int out_base, int out_stride,
                                           int lane, int wave) {
  const int l15 = lane & 15, l4 = lane >> 4;
  const int wc = wave & 7, wr = wave >> 3;
  constexpr int KC = A0KC + A1KC;
  f32x4 acc[4][NFRAG];
  #pragma unroll
  for (int m = 0; m < 4; ++m)
    #pragma unroll
    for (int n = 0; n < NFRAG; ++n) acc[m][n] = (f32x4){0.f, 0.f, 0.f, 0.f};

  const int c0 = wc * (NFRAG * 16);

  // prologue: stage 2 tiles ahead
  stage_B<OUTS>(Wt, wK, 0, lds, 0, wave, lane);
  if (KC > 1) stage_B<OUTS>(Wt, wK, 32, lds, 1, wave, lane);

  #pragma unroll 1
  for (int kc = 0; kc < KC; ++kc) {
    // counted drain: stage(kc) done, stage(kc+1) stays in flight
    if (kc < KC - 1) asm volatile("s_waitcnt vmcnt(1)" ::: "memory");
    else             asm volatile("s_waitcnt vmcnt(0)" ::: "memory");
    __builtin_amdgcn_s_barrier();

    const int buf = kc % 3;
    if (kc + 2 < KC) stage_B<OUTS>(Wt, wK, (kc + 2) * 32, lds, (kc + 2) % 3, wave, lane);

    const int base   = (kc < A0KC) ? a0_base   : a1_base;
    const int stride = (kc < A0KC) ? a0_stride : a1_stride;
    const int kl     = ((kc < A0KC) ? kc : kc - A0KC) * 32;
    bf16x8 a[4];
    #pragma unroll
    for (int m = 0; m < 4; ++m)
      a[m] = *(const bf16x8*)(lds + swz(base, wr * 64 + m * 16 + l15, stride,
                                        (kl + l4 * 8) * 2));
    bf16x8 b[NFRAG];
    #pragma unroll
    for (int n = 0; n < NFRAG; ++n) {
      int col = c0 + n * 16 + l15;
      b[n] = *(const bf16x8*)(lds + B_BASE + buf * 16384 + col * 64 + ((l4 ^ (col & 3)) << 4));
    }

    #pragma unroll
    for (int n = 0; n < NFRAG; ++n)
      #pragma unroll
      for (int m = 0; m < 4; ++m)
        acc[m][n] = __builtin_amdgcn_mfma_f32_16x16x32_bf16(a[m], b[n], acc[m][n], 0, 0, 0);
  }

  // epilogue: all A reads done (last kc fully drained) -> in-place safe
  #pragma unroll
  for (int n = 0; n < NFRAG; ++n) {
    int col = c0 + n * 16 + l15;
    float bv = bias[col];
    #pragma unroll
    for (int m = 0; m < 4; ++m) {
      #pragma unroll
      for (int j = 0; j < 4; ++j) {
        float v = acc[m][n][j] + bv;
        if (RELU) v = fmaxf(v, 0.f);
        int row = wr * 64 + m * 16 + l4 * 4 + j;
        *(bf16*)(lds + swz(out_base, row, out_stride, col * 2)) = (bf16)v;
      }
    }
  }
  __syncthreads();  // epilogue visible; all counters drained
}

// ================= main fused kernel =================
// 16 waves = 2 row-halves x 8 col-groups; each wave 64 rows x NFRAG*16 cols.
__global__ __launch_bounds__(THREADS, 4) void k_main(
    const float* __restrict__ x, const int* __restrict__ ctrl, const int* __restrict__ perm,
    const bf16* __restrict__ wpack,
    const float* __restrict__ b0, const float* __restrict__ bs,
    const float* __restrict__ tb0p, const float* __restrict__ tbsp,
    const float* __restrict__ featb, const float* __restrict__ alphaW,
    const float* __restrict__ alphab, const float* __restrict__ viewsb,
    const float* __restrict__ rgbW, const float* __restrict__ rgbb,
    float* __restrict__ outp) {
  __shared__ __attribute__((aligned(16))) char lds[LDS_BYTES];
  __shared__ int pidx[TILE];
  __shared__ float alpha_s[TILE];

  const int tid = threadIdx.x;
  const int lane = tid & 63, wave = tid >> 6;

  // ---- resolve head + tile from control block ----
  const int tbA = ctrl[24], tbB = ctrl[25], tbC = ctrl[26], tbD = ctrl[27], tbE = ctrl[28];
  const int bid = blockIdx.x;
  if (bid >= tbE) return;
  const int hh = (bid >= tbB) + (bid >= tbC) + (bid >= tbD);
  const int tb_h = (hh == 0) ? tbA : ((hh == 1) ? tbB : ((hh == 2) ? tbC : tbD));
  const int start = ctrl[8 + hh] + (bid - tb_h) * TILE;
  const int nv = min(TILE, ctrl[8 + hh + 1] - start);

  if (tid < TILE) pidx[tid] = (tid < nv) ? perm[start + tid] : -1;
  __syncthreads();

  // ---- pts -> LDS bf16 [128][64] (col 63 = 0, rows>=nv = 0) ----
  for (int i = tid; i < TILE * 64; i += THREADS) {
    int row = i >> 6, c = i & 63;
    int p = pidx[row];
    float v = (p >= 0 && c < 63) ? x[p * 90 + c] : 0.f;
    *(bf16*)(lds + swz(PTS_BASE, row, 128, c * 2)) = (bf16)v;
  }
  __syncthreads();

  const bf16* W0p    = wpack + OFF_W0;
  const bf16* Wsp    = wpack + OFF_WS;
  const bf16* tW0p   = wpack + OFF_TW0 + hh * 81920;
  const bf16* tWsp   = wpack + OFF_TWS + hh * 3 * 65536;
  const bf16* featWp = wpack + OFF_FEATW + hh * 65536;
  const bf16* viewsWp= wpack + OFF_VIEWSW + hh * 36864;

  // trunk: 63->256, 3x 256->256 (in-place H)
  mfma_layer<2, true, 2, 0, 256>(lds, W0p, 64, b0, PTS_BASE, 128, 0, 0, H_BASE, 512, lane, wave);
  mfma_layer<2, true, 8, 0, 256>(lds, Wsp,          256, bs,       H_BASE, 512, 0, 0, H_BASE, 512, lane, wave);
  mfma_layer<2, true, 8, 0, 256>(lds, Wsp + 65536,  256, bs + 256, H_BASE, 512, 0, 0, H_BASE, 512, lane, wave);
  mfma_layer<2, true, 8, 0, 256>(lds, Wsp + 131072, 256, bs + 512, H_BASE, 512, 0, 0, H_BASE, 512, lane, wave);
  // T0: concat(pts, h) 320 -> 256
  mfma_layer<2, true, 2, 8, 256>(lds, tW0p, 320, tb0p + hh * 256,
                                 PTS_BASE, 128, H_BASE, 512, H_BASE, 512, lane, wave);

  // views -> PTS cols 0..31 (T0's PTS reads complete; next reader is the
  // views layer, many barriers later)
  for (int i = tid; i < TILE * 32; i += THREADS) {
    int row = i >> 5, c = i & 31;
    int p = pidx[row];
    float v = (p >= 0 && c < 27) ? x[p * 90 + 63 + c] : 0.f;
    *(bf16*)(lds + swz(PTS_BASE, row, 128, c * 2)) = (bf16)v;
  }

  // head layers
  mfma_layer<2, true, 8, 0, 256>(lds, tWsp,          256, tbsp + hh * 768,       H_BASE, 512, 0, 0, H_BASE, 512, lane, wave);
  mfma_layer<2, true, 8, 0, 256>(lds, tWsp + 65536,  256, tbsp + hh * 768 + 256, H_BASE, 512, 0, 0, H_BASE, 512, lane, wave);
  mfma_layer<2, true, 8, 0, 256>(lds, tWsp + 131072, 256, tbsp + hh * 768 + 512, H_BASE, 512, 0, 0, H_BASE, 512, lane, wave);

  // ---- alpha = ha . alphaW[hh] + alphab (waves 0-7; feat's epilogue can't
  //      overwrite H until all waves pass feat's kc barriers, which happens
  //      after these waves finish alpha) ----
  if (wave < 8) {
    int p = wave * 16 + (lane & 15);
    int kq = lane >> 4;
    const float* aW = alphaW + hh * 256;
    float s = 0.f;
    for (int i = 0; i < 8; ++i) {
      int k = kq * 64 + i * 8;
      bf16x8 hv8 = *(const bf16x8*)(lds + swz(H_BASE, p, 512, k * 2));
      #pragma unroll
      for (int j = 0; j < 8; ++j) s += (float)hv8[j] * aW[k + j];
    }
    s += __shfl_xor(s, 16);
    s += __shfl_xor(s, 32);
    if (kq == 0) alpha_s[p] = s + alphab[hh];
  }

  // feat: 256->256 in-place, NO relu
  mfma_layer<2, false, 8, 0, 256>(lds, featWp, 256, featb + hh * 256,
                                  H_BASE, 512, 0, 0, H_BASE, 512, lane, wave);
  // views: concat(feat, views[32pad]) 288 -> 128, relu, into H cols 0..127
  mfma_layer<1, true, 8, 1, 128>(lds, viewsWp, 288, viewsb + hh * 128,
                                 H_BASE, 512, PTS_BASE, 128, H_BASE, 512, lane, wave);

  // ---- rgb = hv . rgbW[hh] + rgbb ; write float4 {r,g,b,alpha} (waves 0-7) ----
  if (wave < 8) {
    int p = wave * 16 + (lane & 15);
    int kq = lane >> 4;
    const float* rW = rgbW + hh * 128 * 3;
    float r0 = 0.f, r1 = 0.f, r2 = 0.f;
    for (int i = 0; i < 4; ++i) {
      int k = kq * 32 + i * 8;
      bf16x8 hv8 = *(const bf16x8*)(lds + swz(H_BASE, p, 512, k * 2));
      #pragma unroll
      for (int j = 0; j < 8; ++j) {
        float hvf = (float)hv8[j];
        r0 += hvf * rW[(k + j) * 3 + 0];
        r1 += hvf * rW[(k + j) * 3 + 1];
        r2 += hvf * rW[(k + j) * 3 + 2];
      }
    }
    r0 += __shfl_xor(r0, 16); r0 += __shfl_xor(r0, 32);
    r1 += __shfl_xor(r1, 16); r1 += __shfl_xor(r1, 32);
    r2 += __shfl_xor(r2, 16); r2 += __shfl_xor(r2, 32);
    if (kq == 0 && p < nv) {
      int pt = pidx[p];
      float4 o = make_float4(r0 + rgbb[hh * 3 + 0], r1 + rgbb[hh * 3 + 1],
                             r2 + rgbb[hh * 3 + 2], alpha_s[p]);
      *(float4*)(outp + pt * 4) = o;
    }
  }
}

// ================= launch =================
extern "C" void kernel_launch(void* const* d_in, const int* in_sizes, int n_in,
                              void* d_out, int out_size, void* d_ws, size_t ws_size,
                              hipStream_t stream) {
  const float* x      = (const float*)d_in[0];
  const int*   head   = (const int*)d_in[1];
  const float* W0     = (const float*)d_in[2];
  const float* b0     = (const float*)d_in[3];
  const float* Ws     = (const float*)d_in[4];
  const float* bs     = (const float*)d_in[5];
  const float* tW0    = (const float*)d_in[6];
  const float* tb0    = (const float*)d_in[7];
  const float* tWs    = (const float*)d_in[8];
  const float* tbs    = (const float*)d_in[9];
  const float* featW  = (const float*)d_in[10];
  const float* featb  = (const float*)d_in[11];
  const float* alphaW = (const float*)d_in[12];
  const float* alphab = (const float*)d_in[13];
  const float* viewsW = (const float*)d_in[14];
  const float* viewsb = (const float*)d_in[15];
  const float* rgbW   = (const float*)d_in[16];
  const float* rgbb   = (const float*)d_in[17];

  int*  ctrl  = (int*)d_ws;
  int*  perm  = (int*)((char*)d_ws + WS_PERM_OFF);
  bf16* wpack = (bf16*)((char*)d_ws + WS_WPACK_OFF);

  hipMemsetAsync(ctrl, 0, 256, stream);
  k_pack<<<2048, 256, 0, stream>>>(W0, Ws, tW0, tWs, featW, viewsW, wpack, head, ctrl);
  k_scan<<<1, 1, 0, stream>>>(ctrl);
  k_scatter<<<N_PTS / 256, 256, 0, stream>>>(head, ctrl, perm);
  k_main<<<N_PTS / TILE + 4, THREADS, 0, stream>>>(x, ctrl, perm, wpack,
                                                   b0, bs, tb0, tbs, featb, alphaW, alphab,
                                                   viewsb, rgbW, rgbb, (float*)d_out);
}

// Round 11
// 459.651 us; speedup vs baseline: 1.0696x; 1.0659x over previous
//
#include <hip/hip_runtime.h>

#define N_PTS 131072
#define TILE 64
#define THREADS 256

typedef __bf16 bf16;
typedef __bf16 bf16x8 __attribute__((ext_vector_type(8)));
typedef float f32x4 __attribute__((ext_vector_type(4)));

// ---------------- workspace layout (bytes) ----------------
#define WS_PERM_OFF   256                       // int perm[N_PTS]
#define WS_WPACK_OFF  (256 + N_PTS * 4)         // = 524544, bf16 packed weights
// packed-weight element offsets (bf16 elements, all [out][K] "transposed")
#define OFF_W0     0          // [256][64]   (k=63 zero pad)
#define OFF_WS     16384      // [3][256][256]
#define OFF_TW0    212992     // [4][256][320] (k: 0..62 pts, 63 zero, 64..319 h)
#define OFF_TWS    540672     // [12][256][256]
#define OFF_FEATW  1327104    // [4][256][256]
#define OFF_VIEWSW 1589248    // [4][128][288] (k: 0..255 feat, 256..282 views, 283..287 zero)
#define TOTAL_PACK 1736704

// ---------------- LDS layout (bytes) ----------------
// PTS [64][64]bf16 (8KB) + in-place H [64][256]bf16 (32KB)
// + B double-buffer 2 x 16KB = 72KB -> 2 blocks/CU. Cross-block overlap
// (round 7 vs round 10: 1000 vs 2280 cy/step) covers the barrier drains.
#define PTS_BASE 0
#define H_BASE   8192
#define B_BASE   40960
#define LDS_BYTES 73728

__device__ __forceinline__ unsigned swz(unsigned base, unsigned row, unsigned rowstride,
                                        unsigned kbyte) {
  return (base + row * rowstride + kbyte) ^ ((row & 7u) << 4);
}

// async global->LDS, 16B per lane; LDS dest = wave-uniform base + lane*16
__device__ __forceinline__ void gload_lds16(const bf16* g, char* l) {
  __builtin_amdgcn_global_load_lds(
      (const __attribute__((address_space(1))) void*)g,
      (__attribute__((address_space(3))) void*)l, 16, 0, 0);
}

// ================= weight pack (fp32->bf16 transpose) + head count =================
__global__ void k_pack(const float* __restrict__ W0, const float* __restrict__ Ws,
                       const float* __restrict__ tW0, const float* __restrict__ tWs,
                       const float* __restrict__ featW, const float* __restrict__ viewsW,
                       bf16* __restrict__ out, const int* __restrict__ head,
                       int* __restrict__ ctrl) {
  __shared__ int lc[4];
  if (threadIdx.x < 4) lc[threadIdx.x] = 0;
  __syncthreads();
  int gid = blockIdx.x * blockDim.x + threadIdx.x;
  if (gid < N_PTS) atomicAdd(&lc[head[gid]], 1);

  for (int idx = gid; idx < TOTAL_PACK; idx += gridDim.x * blockDim.x) {
    float v;
    if (idx < OFF_WS) {
      int o = idx >> 6, k = idx & 63;
      v = (k < 63) ? W0[k * 256 + o] : 0.f;
    } else if (idx < OFF_TW0) {
      int i = idx - OFF_WS; int l = i >> 16, r = i & 65535, o = r >> 8, k = r & 255;
      v = Ws[l * 65536 + k * 256 + o];
    } else if (idx < OFF_TWS) {
      int i = idx - OFF_TW0; int h = i / 81920, r = i % 81920, o = r / 320, k = r % 320;
      v = (k < 63) ? tW0[(h * 319 + k) * 256 + o]
                   : (k == 63 ? 0.f : tW0[(h * 319 + k - 1) * 256 + o]);
    } else if (idx < OFF_FEATW) {
      int i = idx - OFF_TWS; int hj = i >> 16, r = i & 65535, o = r >> 8, k = r & 255;
      v = tWs[(hj * 256 + k) * 256 + o];
    } else if (idx < OFF_VIEWSW) {
      int i = idx - OFF_FEATW; int h = i >> 16, r = i & 65535, o = r >> 8, k = r & 255;
      v = featW[(h * 256 + k) * 256 + o];
    } else {
      int i = idx - OFF_VIEWSW; int h = i / 36864, r = i % 36864, o = r / 288, k = r % 288;
      v = (k < 283) ? viewsW[(h * 283 + k) * 128 + o] : 0.f;
    }
    out[idx] = (bf16)v;
  }
  __syncthreads();
  if (threadIdx.x < 4 && lc[threadIdx.x]) atomicAdd(&ctrl[threadIdx.x], lc[threadIdx.x]);
}

// ================= bucketing =================
// ctrl ints: [0..3]=counts [8..12]=offsets [16..19]=cursor [24..28]=tile_base
__global__ void k_scan(int* c) {
  c[8] = 0; c[24] = 0;
  for (int h = 0; h < 4; ++h) {
    c[8 + h + 1] = c[8 + h] + c[h];
    c[16 + h] = c[8 + h];
    c[24 + h + 1] = c[24 + h] + (c[h] + TILE - 1) / TILE;
  }
}

__global__ void k_scatter(const int* __restrict__ head, int* __restrict__ c,
                          int* __restrict__ perm) {
  int p = blockIdx.x * 256 + threadIdx.x;
  int h = (p < N_PTS) ? head[p] : -1;
  int lane = threadIdx.x & 63;
  #pragma unroll
  for (int hh = 0; hh < 4; ++hh) {
    unsigned long long m = __ballot(h == hh);
    if (m == 0ull) continue;
    int leader = __builtin_ctzll(m);
    int base = 0;
    if (lane == leader) base = atomicAdd(&c[16 + hh], __popcll(m));
    base = __shfl(base, leader);
    if (h == hh) {
      int rank = __popcll(m & ((1ull << lane) - 1ull));
      perm[base + rank] = p;
    }
  }
}

// ================= B tile staging (global_load_lds) =================
// Tile = B[o][kk..kk+32), o in [0,OUTS). 4 waves x (OUTS/64) 1KB regions.
// LDS slot (o,j) at byte o*64+j*16 holds global k-chunk (j ^ (o&3)):
// source-side XOR swizzle (LDS dest stays linear for global_load_lds)
// -> reader's ds_read is 2-way max.
template <int OUTS>
__device__ __forceinline__ void stage_B(const bf16* __restrict__ Wt, int wK, int kk,
                                        char* lds, int bufsel, int wave, int lane) {
  constexpr int ISSUES = OUTS / 64;   // 4 (OUTS=256) or 2 (OUTS=128)
  #pragma unroll
  for (int s = 0; s < ISSUES; ++s) {
    int reg = wave * ISSUES + s;            // 1KB region index
    int o = reg * 16 + (lane >> 2);
    int j = lane & 3;
    const bf16* g = Wt + o * wK + kk + ((j ^ (o & 3)) << 3);
    gload_lds16(g, lds + B_BASE + bufsel * 16384 + reg * 1024);
  }
}

// ================= fused MLP layer (MFMA, LDS-staged B) =================
// Square per-wave tiles: 4 waves, each 64 rows x NFRAG*16 cols (NFRAG=4 for
// 256-out layers). LDS cost = (4+NFRAG) KB per wave per kc-step serving
// 4*NFRAG MFMAs -> 500 B/MFMA at NFRAG=4 vs 750 at the old 8-wave NFRAG=2
// split (round 7-10 were LDS-BW-bound at ~48KB/step). acc=64 f32 is fine:
// at 2 blocks/CU (LDS-capped) the register budget is 256/thread.
template <int NFRAG, bool RELU, int A0KC, int A1KC, int OUTS>
__device__ __forceinline__ void mfma_layer(char* lds, const bf16* __restrict__ Wt, int wK,
                                           const float* __restrict__ bias,
                                           int a0_base, int a0_stride,
                                           int a1_base, int a1_stride,
                                           int out_base, int out_stride,
                                           int lane, int wave) {
  const int l15 = lane & 15, l4 = lane >> 4;
  constexpr int KC = A0KC + A1KC;
  f32x4 acc[4][NFRAG];
  #pragma unroll
  for (int m = 0; m < 4; ++m)
    #pragma unroll
    for (int n = 0; n < NFRAG; ++n) acc[m][n] = (f32x4){0.f, 0.f, 0.f, 0.f};

  const int c0 = wave * (NFRAG * 16);

  stage_B<OUTS>(Wt, wK, 0, lds, 0, wave, lane);
  __syncthreads();   // drains stage(0); also orders prev layer's epilogue/pts writes

  #pragma unroll 1
  for (int kc = 0; kc < KC; ++kc) {
    const int buf = kc & 1;
    if (kc + 1 < KC) stage_B<OUTS>(Wt, wK, (kc + 1) * 32, lds, buf ^ 1, wave, lane);

    const int base   = (kc < A0KC) ? a0_base   : a1_base;
    const int stride = (kc < A0KC) ? a0_stride : a1_stride;
    const int kl     = ((kc < A0KC) ? kc : kc - A0KC) * 32;
    bf16x8 a[4];
    #pragma unroll
    for (int m = 0; m < 4; ++m)
      a[m] = *(const bf16x8*)(lds + swz(base, m * 16 + l15, stride, (kl + l4 * 8) * 2));

    bf16x8 b[NFRAG];
    #pragma unroll
    for (int n = 0; n < NFRAG; ++n) {
      int col = c0 + n * 16 + l15;
      b[n] = *(const bf16x8*)(lds + B_BASE + buf * 16384 + col * 64 + ((l4 ^ (col & 3)) << 4));
    }

    #pragma unroll
    for (int n = 0; n < NFRAG; ++n)
      #pragma unroll
      for (int m = 0; m < 4; ++m)
        acc[m][n] = __builtin_amdgcn_mfma_f32_16x16x32_bf16(a[m], b[n], acc[m][n], 0, 0, 0);

    __syncthreads();  // buf[kc] consumed; stage(kc+1) drained (vmcnt at barrier)
  }

  // epilogue: all reads done (last kc barrier) -> in-place write is safe
  #pragma unroll
  for (int n = 0; n < NFRAG; ++n) {
    int col = c0 + n * 16 + l15;
    float bv = bias[col];
    #pragma unroll
    for (int m = 0; m < 4; ++m) {
      #pragma unroll
      for (int j = 0; j < 4; ++j) {
        float v = acc[m][n][j] + bv;
        if (RELU) v = fmaxf(v, 0.f);
        int row = m * 16 + l4 * 4 + j;
        *(bf16*)(lds + swz(out_base, row, out_stride, col * 2)) = (bf16)v;
      }
    }
  }
  // no trailing barrier: next layer's head barrier (or explicit one) orders it
}

// ================= main fused kernel =================
// 4 waves x (64 rows x 64 cols); (256,2) = 256-reg budget (spill-free with
// slack), 2 blocks/CU (LDS-capped), cross-block overlap hides barrier drains.
__global__ __launch_bounds__(THREADS, 2) void k_main(
    const float* __restrict__ x, const int* __restrict__ ctrl, const int* __restrict__ perm,
    const bf16* __restrict__ wpack,
    const float* __restrict__ b0, const float* __restrict__ bs,
    const float* __restrict__ tb0p, const float* __restrict__ tbsp,
    const float* __restrict__ featb, const float* __restrict__ alphaW,
    const float* __restrict__ alphab, const float* __restrict__ viewsb,
    const float* __restrict__ rgbW, const float* __restrict__ rgbb,
    float* __restrict__ outp) {
  __shared__ __attribute__((aligned(16))) char lds[LDS_BYTES];
  __shared__ int pidx[TILE];
  __shared__ float alpha_s[TILE];

  const int tid = threadIdx.x;
  const int lane = tid & 63, wave = tid >> 6;

  // ---- resolve head + tile from control block ----
  const int tbA = ctrl[24], tbB = ctrl[25], tbC = ctrl[26], tbD = ctrl[27], tbE = ctrl[28];
  const int bid = blockIdx.x;
  if (bid >= tbE) return;
  const int hh = (bid >= tbB) + (bid >= tbC) + (bid >= tbD);
  const int tb_h = (hh == 0) ? tbA : ((hh == 1) ? tbB : ((hh == 2) ? tbC : tbD));
  const int start = ctrl[8 + hh] + (bid - tb_h) * TILE;
  const int nv = min(TILE, ctrl[8 + hh + 1] - start);

  if (tid < TILE) pidx[tid] = (tid < nv) ? perm[start + tid] : -1;
  __syncthreads();

  // ---- pts -> LDS bf16 [64][64] (col 63 = 0, rows>=nv = 0) ----
  for (int i = tid; i < TILE * 64; i += THREADS) {
    int row = i >> 6, c = i & 63;
    int p = pidx[row];
    float v = (p >= 0 && c < 63) ? x[p * 90 + c] : 0.f;
    *(bf16*)(lds + swz(PTS_BASE, row, 128, c * 2)) = (bf16)v;
  }
  // (no barrier needed: first layer's head barrier orders these writes)

  const bf16* W0p    = wpack + OFF_W0;
  const bf16* Wsp    = wpack + OFF_WS;
  const bf16* tW0p   = wpack + OFF_TW0 + hh * 81920;
  const bf16* tWsp   = wpack + OFF_TWS + hh * 3 * 65536;
  const bf16* featWp = wpack + OFF_FEATW + hh * 65536;
  const bf16* viewsWp= wpack + OFF_VIEWSW + hh * 36864;

  // trunk: 63->256, 3x 256->256 (in-place H)
  mfma_layer<4, true, 2, 0, 256>(lds, W0p, 64, b0, PTS_BASE, 128, 0, 0, H_BASE, 512, lane, wave);
  mfma_layer<4, true, 8, 0, 256>(lds, Wsp,          256, bs,       H_BASE, 512, 0, 0, H_BASE, 512, lane, wave);
  mfma_layer<4, true, 8, 0, 256>(lds, Wsp + 65536,  256, bs + 256, H_BASE, 512, 0, 0, H_BASE, 512, lane, wave);
  mfma_layer<4, true, 8, 0, 256>(lds, Wsp + 131072, 256, bs + 512, H_BASE, 512, 0, 0, H_BASE, 512, lane, wave);
  // T0: concat(pts, h) 320 -> 256
  mfma_layer<4, true, 2, 8, 256>(lds, tW0p, 320, tb0p + hh * 256,
                                 PTS_BASE, 128, H_BASE, 512, H_BASE, 512, lane, wave);

  // views -> PTS cols 0..31 (T0's PTS reads are complete: bounded by its kc
  // barriers; next reader is the views layer, 4 layers of barriers later)
  for (int i = tid; i < TILE * 32; i += THREADS) {
    int row = i >> 5, c = i & 31;
    int p = pidx[row];
    float v = (p >= 0 && c < 27) ? x[p * 90 + 63 + c] : 0.f;
    *(bf16*)(lds + swz(PTS_BASE, row, 128, c * 2)) = (bf16)v;
  }

  // head layers
  mfma_layer<4, true, 8, 0, 256>(lds, tWsp,          256, tbsp + hh * 768,       H_BASE, 512, 0, 0, H_BASE, 512, lane, wave);
  mfma_layer<4, true, 8, 0, 256>(lds, tWsp + 65536,  256, tbsp + hh * 768 + 256, H_BASE, 512, 0, 0, H_BASE, 512, lane, wave);
  mfma_layer<4, true, 8, 0, 256>(lds, tWsp + 131072, 256, tbsp + hh * 768 + 512, H_BASE, 512, 0, 0, H_BASE, 512, lane, wave);

  __syncthreads();  // headL3 epilogue visible before alpha reads

  // ---- alpha = ha . alphaW[hh] + alphab (all 4 waves, 64 points; completes
  //      before feat's epilogue because all waves pass feat's kc barriers) ----
  {
    int p = wave * 16 + (lane & 15);
    int kq = lane >> 4;
    const float* aW = alphaW + hh * 256;
    float s = 0.f;
    for (int i = 0; i < 8; ++i) {
      int k = kq * 64 + i * 8;
      bf16x8 hv8 = *(const bf16x8*)(lds + swz(H_BASE, p, 512, k * 2));
      #pragma unroll
      for (int j = 0; j < 8; ++j) s += (float)hv8[j] * aW[k + j];
    }
    s += __shfl_xor(s, 16);
    s += __shfl_xor(s, 32);
    if (kq == 0) alpha_s[p] = s + alphab[hh];
  }

  // feat: 256->256 in-place, NO relu
  mfma_layer<4, false, 8, 0, 256>(lds, featWp, 256, featb + hh * 256,
                                  H_BASE, 512, 0, 0, H_BASE, 512, lane, wave);
  // views: concat(feat, views[32pad]) 288 -> 128, relu, into H cols 0..127
  mfma_layer<2, true, 8, 1, 128>(lds, viewsWp, 288, viewsb + hh * 128,
                                 H_BASE, 512, PTS_BASE, 128, H_BASE, 512, lane, wave);

  __syncthreads();  // views epilogue visible before rgb reads

  // ---- rgb = hv . rgbW[hh] + rgbb ; write float4 {r,g,b,alpha} ----
  {
    int p = wave * 16 + (lane & 15);
    int kq = lane >> 4;
    const float* rW = rgbW + hh * 128 * 3;
    float r0 = 0.f, r1 = 0.f, r2 = 0.f;
    for (int i = 0; i < 4; ++i) {
      int k = kq * 32 + i * 8;
      bf16x8 hv8 = *(const bf16x8*)(lds + swz(H_BASE, p, 512, k * 2));
      #pragma unroll
      for (int j = 0; j < 8; ++j) {
        float hvf = (float)hv8[j];
        r0 += hvf * rW[(k + j) * 3 + 0];
        r1 += hvf * rW[(k + j) * 3 + 1];
        r2 += hvf * rW[(k + j) * 3 + 2];
      }
    }
    r0 += __shfl_xor(r0, 16); r0 += __shfl_xor(r0, 32);
    r1 += __shfl_xor(r1, 16); r1 += __shfl_xor(r1, 32);
    r2 += __shfl_xor(r2, 16); r2 += __shfl_xor(r2, 32);
    if (kq == 0 && p < nv) {
      int pt = pidx[p];
      float4 o = make_float4(r0 + rgbb[hh * 3 + 0], r1 + rgbb[hh * 3 + 1],
                             r2 + rgbb[hh * 3 + 2], alpha_s[p]);
      *(float4*)(outp + pt * 4) = o;
    }
  }
}

// ================= launch =================
extern "C" void kernel_launch(void* const* d_in, const int* in_sizes, int n_in,
                              void* d_out, int out_size, void* d_ws, size_t ws_size,
                              hipStream_t stream) {
  const float* x      = (const float*)d_in[0];
  const int*   head   = (const int*)d_in[1];
  const float* W0     = (const float*)d_in[2];
  const float* b0     = (const float*)d_in[3];
  const float* Ws     = (const float*)d_in[4];
  const float* bs     = (const float*)d_in[5];
  const float* tW0    = (const float*)d_in[6];
  const float* tb0    = (const float*)d_in[7];
  const float* tWs    = (const float*)d_in[8];
  const float* tbs    = (const float*)d_in[9];
  const float* featW  = (const float*)d_in[10];
  const float* featb  = (const float*)d_in[11];
  const float* alphaW = (const float*)d_in[12];
  const float* alphab = (const float*)d_in[13];
  const float* viewsW = (const float*)d_in[14];
  const float* viewsb = (const float*)d_in[15];
  const float* rgbW   = (const float*)d_in[16];
  const float* rgbb   = (const float*)d_in[17];

  int*  ctrl  = (int*)d_ws;
  int*  perm  = (int*)((char*)d_ws + WS_PERM_OFF);
  bf16* wpack = (bf16*)((char*)d_ws + WS_WPACK_OFF);

  hipMemsetAsync(ctrl, 0, 256, stream);
  k_pack<<<2048, 256, 0, stream>>>(W0, Ws, tW0, tWs, featW, viewsW, wpack, head, ctrl);
  k_scan<<<1, 1, 0, stream>>>(ctrl);
  k_scatter<<<N_PTS / 256, 256, 0, stream>>>(head, ctrl, perm);
  k_main<<<N_PTS / TILE + 4, THREADS, 0, stream>>>(x, ctrl, perm, wpack,
                                                   b0, bs, tb0, tbs, featb, alphaW, alphab,
                                                   viewsb, rgbW, rgbb, (float*)d_out);
}

// Round 12
// 455.137 us; speedup vs baseline: 1.0803x; 1.0099x over previous
//
#include <hip/hip_runtime.h>

#define N_PTS 131072
#define TILE 64
#define THREADS 256

typedef __bf16 bf16;
typedef __bf16 bf16x8 __attribute__((ext_vector_type(8)));
typedef float f32x4 __attribute__((ext_vector_type(4)));

// ---------------- workspace layout (bytes) ----------------
#define WS_PERM_OFF   256                       // int perm[N_PTS]
#define WS_WPACK_OFF  (256 + N_PTS * 4)         // = 524544, bf16 packed weights
// packed-weight element offsets (bf16 elements, all [out][K] "transposed")
#define OFF_W0     0          // [256][64]   (k=63 zero pad)
#define OFF_WS     16384      // [3][256][256]
#define OFF_TW0    212992     // [4][256][320] (k: 0..62 pts, 63 zero, 64..319 h)
#define OFF_TWS    540672     // [12][256][256]
#define OFF_FEATW  1327104    // [4][256][256]
#define OFF_VIEWSW 1589248    // [4][128][288] (k: 0..255 feat, 256..282 views, 283..287 zero)
#define TOTAL_PACK 1736704

// ---------------- LDS layout (bytes) ----------------
// PTS [64][64]bf16 (8KB) + in-place H [64][256]bf16 (32KB)
// + B double-buffer 2 x 16KB = 72KB -> 2 blocks/CU (cross-block overlap).
#define PTS_BASE 0
#define H_BASE   8192
#define B_BASE   40960
#define LDS_BYTES 73728

__device__ __forceinline__ unsigned swz(unsigned base, unsigned row, unsigned rowstride,
                                        unsigned kbyte) {
  return (base + row * rowstride + kbyte) ^ ((row & 7u) << 4);
}

// async global->LDS, 16B per lane; LDS dest = wave-uniform base + lane*16
__device__ __forceinline__ void gload_lds16(const bf16* g, char* l) {
  __builtin_amdgcn_global_load_lds(
      (const __attribute__((address_space(1))) void*)g,
      (__attribute__((address_space(3))) void*)l, 16, 0, 0);
}

// ================= weight pack (fp32->bf16 transpose) + head count =================
__global__ void k_pack(const float* __restrict__ W0, const float* __restrict__ Ws,
                       const float* __restrict__ tW0, const float* __restrict__ tWs,
                       const float* __restrict__ featW, const float* __restrict__ viewsW,
                       bf16* __restrict__ out, const int* __restrict__ head,
                       int* __restrict__ ctrl) {
  __shared__ int lc[4];
  if (threadIdx.x < 4) lc[threadIdx.x] = 0;
  __syncthreads();
  int gid = blockIdx.x * blockDim.x + threadIdx.x;
  if (gid < N_PTS) atomicAdd(&lc[head[gid]], 1);

  for (int idx = gid; idx < TOTAL_PACK; idx += gridDim.x * blockDim.x) {
    float v;
    if (idx < OFF_WS) {
      int o = idx >> 6, k = idx & 63;
      v = (k < 63) ? W0[k * 256 + o] : 0.f;
    } else if (idx < OFF_TW0) {
      int i = idx - OFF_WS; int l = i >> 16, r = i & 65535, o = r >> 8, k = r & 255;
      v = Ws[l * 65536 + k * 256 + o];
    } else if (idx < OFF_TWS) {
      int i = idx - OFF_TW0; int h = i / 81920, r = i % 81920, o = r / 320, k = r % 320;
      v = (k < 63) ? tW0[(h * 319 + k) * 256 + o]
                   : (k == 63 ? 0.f : tW0[(h * 319 + k - 1) * 256 + o]);
    } else if (idx < OFF_FEATW) {
      int i = idx - OFF_TWS; int hj = i >> 16, r = i & 65535, o = r >> 8, k = r & 255;
      v = tWs[(hj * 256 + k) * 256 + o];
    } else if (idx < OFF_VIEWSW) {
      int i = idx - OFF_FEATW; int h = i >> 16, r = i & 65535, o = r >> 8, k = r & 255;
      v = featW[(h * 256 + k) * 256 + o];
    } else {
      int i = idx - OFF_VIEWSW; int h = i / 36864, r = i % 36864, o = r / 288, k = r % 288;
      v = (k < 283) ? viewsW[(h * 283 + k) * 128 + o] : 0.f;
    }
    out[idx] = (bf16)v;
  }
  __syncthreads();
  if (threadIdx.x < 4 && lc[threadIdx.x]) atomicAdd(&ctrl[threadIdx.x], lc[threadIdx.x]);
}

// ================= bucketing =================
// ctrl ints: [0..3]=counts [8..12]=offsets [16..19]=cursor [24..28]=tile_base
__global__ void k_scan(int* c) {
  c[8] = 0; c[24] = 0;
  for (int h = 0; h < 4; ++h) {
    c[8 + h + 1] = c[8 + h] + c[h];
    c[16 + h] = c[8 + h];
    c[24 + h + 1] = c[24 + h] + (c[h] + TILE - 1) / TILE;
  }
}

__global__ void k_scatter(const int* __restrict__ head, int* __restrict__ c,
                          int* __restrict__ perm) {
  int p = blockIdx.x * 256 + threadIdx.x;
  int h = (p < N_PTS) ? head[p] : -1;
  int lane = threadIdx.x & 63;
  #pragma unroll
  for (int hh = 0; hh < 4; ++hh) {
    unsigned long long m = __ballot(h == hh);
    if (m == 0ull) continue;
    int leader = __builtin_ctzll(m);
    int base = 0;
    if (lane == leader) base = atomicAdd(&c[16 + hh], __popcll(m));
    base = __shfl(base, leader);
    if (h == hh) {
      int rank = __popcll(m & ((1ull << lane) - 1ull));
      perm[base + rank] = p;
    }
  }
}

// ================= B tile staging (global_load_lds) =================
// Tile = B[o][kk..kk+32), o in [0,OUTS). 4 waves x (OUTS/64) 1KB regions.
// LDS slot (o,j) at byte o*64+j*16 holds global k-chunk (j ^ ((o>>1)&3)).
// Reader slot = l4 ^ ((col>>1)&3) -> bank_start = 16*(col&1)+4*(l4^((col>>1)&3))
// spreads 16 l15-lanes over all 8 16B slots = 2-way (free). Round-11's
// (o&3) variant collided cols {0,4,8,12} 4-way (1.9e7 conflict cycles).
template <int OUTS>
__device__ __forceinline__ void stage_B(const bf16* __restrict__ Wt, int wK, int kk,
                                        char* lds, int bufsel, int wave, int lane) {
  constexpr int ISSUES = OUTS / 64;   // 4 (OUTS=256) or 2 (OUTS=128)
  #pragma unroll
  for (int s = 0; s < ISSUES; ++s) {
    int reg = wave * ISSUES + s;            // 1KB region index
    int o = reg * 16 + (lane >> 2);
    int j = lane & 3;
    const bf16* g = Wt + o * wK + kk + ((j ^ ((o >> 1) & 3)) << 3);
    gload_lds16(g, lds + B_BASE + bufsel * 16384 + reg * 1024);
  }
}

// ================= fused MLP layer (MFMA, pipelined LDS-staged B) =================
// T3 minimum-2-phase structure: per kc-step
//   s_waitcnt vmcnt(0)   <- drains stage(kc), issued ONE FULL STEP earlier
//   s_barrier            <- all waves' stage(kc) landed; buf(kc) complete
//   stage(kc+1)          <- issued EARLY; has the whole compute phase to land
//   ds_read A,B; 16 MFMA
// vs round 7-11's trailing __syncthreads() whose implicit vmcnt(0) drained a
// stage issued ~200cy earlier -> each of 77 steps serially exposed an L2
// round-trip (the invariant ~2860 cy/block-step across rounds 7/10/11).
// WAR safety: stage(kc+1) writes buf(kc-1), whose readers (step kc-1)
// completed their ds_reads before their MFMAs, hence before this barrier.
template <int NFRAG, bool RELU, int A0KC, int A1KC, int OUTS>
__device__ __forceinline__ void mfma_layer(char* lds, const bf16* __restrict__ Wt, int wK,
                                           const float* __restrict__ bias,
                                           int a0_base, int a0_stride,
                                           int a1_base, int a1_stride,
                                           int out_base, int out_stride,
                                           int lane, int wave) {
  const int l15 = lane & 15, l4 = lane >> 4;
  constexpr int KC = A0KC + A1KC;
  f32x4 acc[4][NFRAG];
  #pragma unroll
  for (int m = 0; m < 4; ++m)
    #pragma unroll
    for (int n = 0; n < NFRAG; ++n) acc[m][n] = (f32x4){0.f, 0.f, 0.f, 0.f};

  const int c0 = wave * (NFRAG * 16);

  stage_B<OUTS>(Wt, wK, 0, lds, 0, wave, lane);

  #pragma unroll 1
  for (int kc = 0; kc < KC; ++kc) {
    asm volatile("s_waitcnt vmcnt(0)" ::: "memory");  // stage(kc) landed (one step of slack)
    __builtin_amdgcn_s_barrier();

    const int buf = kc & 1;
    if (kc + 1 < KC) stage_B<OUTS>(Wt, wK, (kc + 1) * 32, lds, buf ^ 1, wave, lane);

    const int base   = (kc < A0KC) ? a0_base   : a1_base;
    const int stride = (kc < A0KC) ? a0_stride : a1_stride;
    const int kl     = ((kc < A0KC) ? kc : kc - A0KC) * 32;
    bf16x8 a[4];
    #pragma unroll
    for (int m = 0; m < 4; ++m)
      a[m] = *(const bf16x8*)(lds + swz(base, m * 16 + l15, stride, (kl + l4 * 8) * 2));

    bf16x8 b[NFRAG];
    #pragma unroll
    for (int n = 0; n < NFRAG; ++n) {
      int col = c0 + n * 16 + l15;
      b[n] = *(const bf16x8*)(lds + B_BASE + buf * 16384 + col * 64 +
                              ((l4 ^ ((col >> 1) & 3)) << 4));
    }

    #pragma unroll
    for (int n = 0; n < NFRAG; ++n)
      #pragma unroll
      for (int m = 0; m < 4; ++m)
        acc[m][n] = __builtin_amdgcn_mfma_f32_16x16x32_bf16(a[m], b[n], acc[m][n], 0, 0, 0);
  }

  // all waves' A-reads complete (reads precede MFMAs precede this barrier)
  __builtin_amdgcn_s_barrier();

  // epilogue: in-place write now safe
  #pragma unroll
  for (int n = 0; n < NFRAG; ++n) {
    int col = c0 + n * 16 + l15;
    float bv = bias[col];
    #pragma unroll
    for (int m = 0; m < 4; ++m) {
      #pragma unroll
      for (int j = 0; j < 4; ++j) {
        float v = acc[m][n][j] + bv;
        if (RELU) v = fmaxf(v, 0.f);
        int row = m * 16 + l4 * 4 + j;
        *(bf16*)(lds + swz(out_base, row, out_stride, col * 2)) = (bf16)v;
      }
    }
  }
  __syncthreads();  // full drain (lgkmcnt): epilogue visible to next layer
}

// ================= main fused kernel =================
// 4 waves x (64 rows x 64 cols); (256,2) = 256-reg budget (spill-free,
// r11: VGPR 124 / WRITE 3.7MB), 2 blocks/CU, pipelined stage.
__global__ __launch_bounds__(THREADS, 2) void k_main(
    const float* __restrict__ x, const int* __restrict__ ctrl, const int* __restrict__ perm,
    const bf16* __restrict__ wpack,
    const float* __restrict__ b0, const float* __restrict__ bs,
    const float* __restrict__ tb0p, const float* __restrict__ tbsp,
    const float* __restrict__ featb, const float* __restrict__ alphaW,
    const float* __restrict__ alphab, const float* __restrict__ viewsb,
    const float* __restrict__ rgbW, const float* __restrict__ rgbb,
    float* __restrict__ outp) {
  __shared__ __attribute__((aligned(16))) char lds[LDS_BYTES];
  __shared__ int pidx[TILE];
  __shared__ float alpha_s[TILE];

  const int tid = threadIdx.x;
  const int lane = tid & 63, wave = tid >> 6;

  // ---- resolve head + tile from control block ----
  const int tbA = ctrl[24], tbB = ctrl[25], tbC = ctrl[26], tbD = ctrl[27], tbE = ctrl[28];
  const int bid = blockIdx.x;
  if (bid >= tbE) return;
  const int hh = (bid >= tbB) + (bid >= tbC) + (bid >= tbD);
  const int tb_h = (hh == 0) ? tbA : ((hh == 1) ? tbB : ((hh == 2) ? tbC : tbD));
  const int start = ctrl[8 + hh] + (bid - tb_h) * TILE;
  const int nv = min(TILE, ctrl[8 + hh + 1] - start);

  if (tid < TILE) pidx[tid] = (tid < nv) ? perm[start + tid] : -1;
  __syncthreads();

  // ---- pts -> LDS bf16 [64][64] (col 63 = 0, rows>=nv = 0) ----
  for (int i = tid; i < TILE * 64; i += THREADS) {
    int row = i >> 6, c = i & 63;
    int p = pidx[row];
    float v = (p >= 0 && c < 63) ? x[p * 90 + c] : 0.f;
    *(bf16*)(lds + swz(PTS_BASE, row, 128, c * 2)) = (bf16)v;
  }
  __syncthreads();  // pts visible before W0's raw-barrier loop reads them

  const bf16* W0p    = wpack + OFF_W0;
  const bf16* Wsp    = wpack + OFF_WS;
  const bf16* tW0p   = wpack + OFF_TW0 + hh * 81920;
  const bf16* tWsp   = wpack + OFF_TWS + hh * 3 * 65536;
  const bf16* featWp = wpack + OFF_FEATW + hh * 65536;
  const bf16* viewsWp= wpack + OFF_VIEWSW + hh * 36864;

  // trunk: 63->256, 3x 256->256 (in-place H)
  mfma_layer<4, true, 2, 0, 256>(lds, W0p, 64, b0, PTS_BASE, 128, 0, 0, H_BASE, 512, lane, wave);
  mfma_layer<4, true, 8, 0, 256>(lds, Wsp,          256, bs,       H_BASE, 512, 0, 0, H_BASE, 512, lane, wave);
  mfma_layer<4, true, 8, 0, 256>(lds, Wsp + 65536,  256, bs + 256, H_BASE, 512, 0, 0, H_BASE, 512, lane, wave);
  mfma_layer<4, true, 8, 0, 256>(lds, Wsp + 131072, 256, bs + 512, H_BASE, 512, 0, 0, H_BASE, 512, lane, wave);
  // T0: concat(pts, h) 320 -> 256
  mfma_layer<4, true, 2, 8, 256>(lds, tW0p, 320, tb0p + hh * 256,
                                 PTS_BASE, 128, H_BASE, 512, H_BASE, 512, lane, wave);

  // views -> PTS cols 0..31 (T0's PTS reads complete before its epilogue barrier)
  for (int i = tid; i < TILE * 32; i += THREADS) {
    int row = i >> 5, c = i & 31;
    int p = pidx[row];
    float v = (p >= 0 && c < 27) ? x[p * 90 + 63 + c] : 0.f;
    *(bf16*)(lds + swz(PTS_BASE, row, 128, c * 2)) = (bf16)v;
  }
  __syncthreads();  // views-gather writes drained before later raw-barrier layers

  // head layers
  mfma_layer<4, true, 8, 0, 256>(lds, tWsp,          256, tbsp + hh * 768,       H_BASE, 512, 0, 0, H_BASE, 512, lane, wave);
  mfma_layer<4, true, 8, 0, 256>(lds, tWsp + 65536,  256, tbsp + hh * 768 + 256, H_BASE, 512, 0, 0, H_BASE, 512, lane, wave);
  mfma_layer<4, true, 8, 0, 256>(lds, tWsp + 131072, 256, tbsp + hh * 768 + 512, H_BASE, 512, 0, 0, H_BASE, 512, lane, wave);

  // ---- alpha = ha . alphaW[hh] + alphab (all 4 waves, 64 points; completes
  //      before feat's epilogue because all waves pass feat's kc barriers) ----
  {
    int p = wave * 16 + (lane & 15);
    int kq = lane >> 4;
    const float* aW = alphaW + hh * 256;
    float s = 0.f;
    for (int i = 0; i < 8; ++i) {
      int k = kq * 64 + i * 8;
      bf16x8 hv8 = *(const bf16x8*)(lds + swz(H_BASE, p, 512, k * 2));
      #pragma unroll
      for (int j = 0; j < 8; ++j) s += (float)hv8[j] * aW[k + j];
    }
    s += __shfl_xor(s, 16);
    s += __shfl_xor(s, 32);
    if (kq == 0) alpha_s[p] = s + alphab[hh];
  }

  // feat: 256->256 in-place, NO relu
  mfma_layer<4, false, 8, 0, 256>(lds, featWp, 256, featb + hh * 256,
                                  H_BASE, 512, 0, 0, H_BASE, 512, lane, wave);
  // views: concat(feat, views[32pad]) 288 -> 128, relu, into H cols 0..127
  mfma_layer<2, true, 8, 1, 128>(lds, viewsWp, 288, viewsb + hh * 128,
                                 H_BASE, 512, PTS_BASE, 128, H_BASE, 512, lane, wave);

  // ---- rgb = hv . rgbW[hh] + rgbb ; write float4 {r,g,b,alpha} ----
  {
    int p = wave * 16 + (lane & 15);
    int kq = lane >> 4;
    const float* rW = rgbW + hh * 128 * 3;
    float r0 = 0.f, r1 = 0.f, r2 = 0.f;
    for (int i = 0; i < 4; ++i) {
      int k = kq * 32 + i * 8;
      bf16x8 hv8 = *(const bf16x8*)(lds + swz(H_BASE, p, 512, k * 2));
      #pragma unroll
      for (int j = 0; j < 8; ++j) {
        float hvf = (float)hv8[j];
        r0 += hvf * rW[(k + j) * 3 + 0];
        r1 += hvf * rW[(k + j) * 3 + 1];
        r2 += hvf * rW[(k + j) * 3 + 2];
      }
    }
    r0 += __shfl_xor(r0, 16); r0 += __shfl_xor(r0, 32);
    r1 += __shfl_xor(r1, 16); r1 += __shfl_xor(r1, 32);
    r2 += __shfl_xor(r2, 16); r2 += __shfl_xor(r2, 32);
    if (kq == 0 && p < nv) {
      int pt = pidx[p];
      float4 o = make_float4(r0 + rgbb[hh * 3 + 0], r1 + rgbb[hh * 3 + 1],
                             r2 + rgbb[hh * 3 + 2], alpha_s[p]);
      *(float4*)(outp + pt * 4) = o;
    }
  }
}

// ================= launch =================
extern "C" void kernel_launch(void* const* d_in, const int* in_sizes, int n_in,
                              void* d_out, int out_size, void* d_ws, size_t ws_size,
                              hipStream_t stream) {
  const float* x      = (const float*)d_in[0];
  const int*   head   = (const int*)d_in[1];
  const float* W0     = (const float*)d_in[2];
  const float* b0     = (const float*)d_in[3];
  const float* Ws     = (const float*)d_in[4];
  const float* bs     = (const float*)d_in[5];
  const float* tW0    = (const float*)d_in[6];
  const float* tb0    = (const float*)d_in[7];
  const float* tWs    = (const float*)d_in[8];
  const float* tbs    = (const float*)d_in[9];
  const float* featW  = (const float*)d_in[10];
  const float* featb  = (const float*)d_in[11];
  const float* alphaW = (const float*)d_in[12];
  const float* alphab = (const float*)d_in[13];
  const float* viewsW = (const float*)d_in[14];
  const float* viewsb = (const float*)d_in[15];
  const float* rgbW   = (const float*)d_in[16];
  const float* rgbb   = (const float*)d_in[17];

  int*  ctrl  = (int*)d_ws;
  int*  perm  = (int*)((char*)d_ws + WS_PERM_OFF);
  bf16* wpack = (bf16*)((char*)d_ws + WS_WPACK_OFF);

  hipMemsetAsync(ctrl, 0, 256, stream);
  k_pack<<<2048, 256, 0, stream>>>(W0, Ws, tW0, tWs, featW, viewsW, wpack, head, ctrl);
  k_scan<<<1, 1, 0, stream>>>(ctrl);
  k_scatter<<<N_PTS / 256, 256, 0, stream>>>(head, ctrl, perm);
  k_main<<<N_PTS / TILE + 4, THREADS, 0, stream>>>(x, ctrl, perm, wpack,
                                                   b0, bs, tb0, tbs, featb, alphaW, alphab,
                                                   viewsb, rgbW, rgbb, (float*)d_out);
}

// Round 13
// 423.828 us; speedup vs baseline: 1.1601x; 1.0739x over previous
//
#include <hip/hip_runtime.h>

#define N_PTS 131072
#define TILE 64
#define THREADS 512

typedef __bf16 bf16;
typedef __bf16 bf16x8 __attribute__((ext_vector_type(8)));
typedef float f32x4 __attribute__((ext_vector_type(4)));

// ---------------- workspace layout (bytes) ----------------
#define WS_PERM_OFF   256                       // int perm[N_PTS]
#define WS_WPACK_OFF  (256 + N_PTS * 4)         // = 524544, bf16 packed weights
// packed-weight element offsets (bf16 elements, all [out][K] "transposed")
#define OFF_W0     0          // [256][64]   (k=63 zero pad)
#define OFF_WS     16384      // [3][256][256]
#define OFF_TW0    212992     // [4][256][320] (k: 0..62 pts, 63 zero, 64..319 h)
#define OFF_TWS    540672     // [12][256][256]
#define OFF_FEATW  1327104    // [4][256][256]
#define OFF_VIEWSW 1589248    // [4][128][288] (k: 0..255 feat, 256..282 views, 283..287 zero)
#define TOTAL_PACK 1736704

// ---------------- LDS layout (bytes) ----------------
// PTS [64][64]bf16 (8KB) + in-place H [64][256]bf16 (32KB)
// + B double-buffer 2 x 16KB = 72KB -> 2 blocks/CU.
// 512-thr/8-wave blocks: 16 waves/CU = 4 waves/SIMD (r12 had only 2 --
// the tested-spill-free occupancy doubling).
#define PTS_BASE 0
#define H_BASE   8192
#define B_BASE   40960
#define LDS_BYTES 73728

__device__ __forceinline__ unsigned swz(unsigned base, unsigned row, unsigned rowstride,
                                        unsigned kbyte) {
  return (base + row * rowstride + kbyte) ^ ((row & 7u) << 4);
}

// async global->LDS, 16B per lane; LDS dest = wave-uniform base + lane*16
__device__ __forceinline__ void gload_lds16(const bf16* g, char* l) {
  __builtin_amdgcn_global_load_lds(
      (const __attribute__((address_space(1))) void*)g,
      (__attribute__((address_space(3))) void*)l, 16, 0, 0);
}

// ================= weight pack (fp32->bf16 transpose) + head count =================
__global__ void k_pack(const float* __restrict__ W0, const float* __restrict__ Ws,
                       const float* __restrict__ tW0, const float* __restrict__ tWs,
                       const float* __restrict__ featW, const float* __restrict__ viewsW,
                       bf16* __restrict__ out, const int* __restrict__ head,
                       int* __restrict__ ctrl) {
  __shared__ int lc[4];
  if (threadIdx.x < 4) lc[threadIdx.x] = 0;
  __syncthreads();
  int gid = blockIdx.x * blockDim.x + threadIdx.x;
  if (gid < N_PTS) atomicAdd(&lc[head[gid]], 1);

  for (int idx = gid; idx < TOTAL_PACK; idx += gridDim.x * blockDim.x) {
    float v;
    if (idx < OFF_WS) {
      int o = idx >> 6, k = idx & 63;
      v = (k < 63) ? W0[k * 256 + o] : 0.f;
    } else if (idx < OFF_TW0) {
      int i = idx - OFF_WS; int l = i >> 16, r = i & 65535, o = r >> 8, k = r & 255;
      v = Ws[l * 65536 + k * 256 + o];
    } else if (idx < OFF_TWS) {
      int i = idx - OFF_TW0; int h = i / 81920, r = i % 81920, o = r / 320, k = r % 320;
      v = (k < 63) ? tW0[(h * 319 + k) * 256 + o]
                   : (k == 63 ? 0.f : tW0[(h * 319 + k - 1) * 256 + o]);
    } else if (idx < OFF_FEATW) {
      int i = idx - OFF_TWS; int hj = i >> 16, r = i & 65535, o = r >> 8, k = r & 255;
      v = tWs[(hj * 256 + k) * 256 + o];
    } else if (idx < OFF_VIEWSW) {
      int i = idx - OFF_FEATW; int h = i >> 16, r = i & 65535, o = r >> 8, k = r & 255;
      v = featW[(h * 256 + k) * 256 + o];
    } else {
      int i = idx - OFF_VIEWSW; int h = i / 36864, r = i % 36864, o = r / 288, k = r % 288;
      v = (k < 283) ? viewsW[(h * 283 + k) * 128 + o] : 0.f;
    }
    out[idx] = (bf16)v;
  }
  __syncthreads();
  if (threadIdx.x < 4 && lc[threadIdx.x]) atomicAdd(&ctrl[threadIdx.x], lc[threadIdx.x]);
}

// ================= bucketing =================
// ctrl ints: [0..3]=counts [8..12]=offsets [16..19]=cursor [24..28]=tile_base
__global__ void k_scan(int* c) {
  c[8] = 0; c[24] = 0;
  for (int h = 0; h < 4; ++h) {
    c[8 + h + 1] = c[8 + h] + c[h];
    c[16 + h] = c[8 + h];
    c[24 + h + 1] = c[24 + h] + (c[h] + TILE - 1) / TILE;
  }
}

__global__ void k_scatter(const int* __restrict__ head, int* __restrict__ c,
                          int* __restrict__ perm) {
  int p = blockIdx.x * 256 + threadIdx.x;
  int h = (p < N_PTS) ? head[p] : -1;
  int lane = threadIdx.x & 63;
  #pragma unroll
  for (int hh = 0; hh < 4; ++hh) {
    unsigned long long m = __ballot(h == hh);
    if (m == 0ull) continue;
    int leader = __builtin_ctzll(m);
    int base = 0;
    if (lane == leader) base = atomicAdd(&c[16 + hh], __popcll(m));
    base = __shfl(base, leader);
    if (h == hh) {
      int rank = __popcll(m & ((1ull << lane) - 1ull));
      perm[base + rank] = p;
    }
  }
}

// ================= B tile staging (global_load_lds) =================
// Tile = B[o][kk..kk+32), o in [0,OUTS). 8 waves x (OUTS/128) 1KB regions.
// LDS slot (o,j) at byte o*64+j*16 holds global k-chunk (j ^ ((o>>1)&3)).
// Reader slot = l4 ^ ((col>>1)&3) -> 16 l15-lanes spread over all 8 16B
// slots = 2-way (free); verified r12: conflicts 1.9e7 -> 9.6e6.
template <int OUTS>
__device__ __forceinline__ void stage_B(const bf16* __restrict__ Wt, int wK, int kk,
                                        char* lds, int bufsel, int wave, int lane) {
  constexpr int ISSUES = OUTS / 128;   // 2 (OUTS=256) or 1 (OUTS=128)
  #pragma unroll
  for (int s = 0; s < ISSUES; ++s) {
    int reg = wave * ISSUES + s;            // 1KB region index
    int o = reg * 16 + (lane >> 2);
    int j = lane & 3;
    const bf16* g = Wt + o * wK + kk + ((j ^ ((o >> 1) & 3)) << 3);
    gload_lds16(g, lds + B_BASE + bufsel * 16384 + reg * 1024);
  }
}

// ================= fused MLP layer (MFMA, pipelined LDS-staged B) =================
// 8 waves as 2 row-groups (wr) x 4 col-groups (wc): wave tile = MR*16 rows x
// NF*16 cols (32x64 for 256-out layers). acc = MR*NF = 8 f32x4 = 32 regs ->
// demand ~90 fits the (512,4) 128-reg budget (B is zero-reg via gload_lds).
// Per kc-step (r12's proven T3 2-phase):
//   s_waitcnt vmcnt(0)  <- stage(kc), issued one compute-phase earlier
//   s_barrier           <- buf(kc) complete for all waves
//   stage(kc+1)         <- issued early, lands during compute
//   ds_read A,B; setprio(1); 8 MFMA; setprio(0)
template <int MR, int NF, bool RELU, int A0KC, int A1KC, int OUTS>
__device__ __forceinline__ void mfma_layer(char* lds, const bf16* __restrict__ Wt, int wK,
                                           const float* __restrict__ bias,
                                           int a0_base, int a0_stride,
                                           int a1_base, int a1_stride,
                                           int out_base, int out_stride,
                                           int lane, int wave) {
  const int l15 = lane & 15, l4 = lane >> 4;
  const int wr = wave >> 2, wc = wave & 3;
  constexpr int KC = A0KC + A1KC;
  f32x4 acc[MR][NF];
  #pragma unroll
  for (int m = 0; m < MR; ++m)
    #pragma unroll
    for (int n = 0; n < NF; ++n) acc[m][n] = (f32x4){0.f, 0.f, 0.f, 0.f};

  const int r0 = wr * (MR * 16);
  const int c0 = wc * (NF * 16);

  stage_B<OUTS>(Wt, wK, 0, lds, 0, wave, lane);

  #pragma unroll 1
  for (int kc = 0; kc < KC; ++kc) {
    asm volatile("s_waitcnt vmcnt(0)" ::: "memory");  // stage(kc) landed
    __builtin_amdgcn_s_barrier();

    const int buf = kc & 1;
    if (kc + 1 < KC) stage_B<OUTS>(Wt, wK, (kc + 1) * 32, lds, buf ^ 1, wave, lane);

    const int base   = (kc < A0KC) ? a0_base   : a1_base;
    const int stride = (kc < A0KC) ? a0_stride : a1_stride;
    const int kl     = ((kc < A0KC) ? kc : kc - A0KC) * 32;
    bf16x8 a[MR];
    #pragma unroll
    for (int m = 0; m < MR; ++m)
      a[m] = *(const bf16x8*)(lds + swz(base, r0 + m * 16 + l15, stride,
                                        (kl + l4 * 8) * 2));
    bf16x8 b[NF];
    #pragma unroll
    for (int n = 0; n < NF; ++n) {
      int col = c0 + n * 16 + l15;
      b[n] = *(const bf16x8*)(lds + B_BASE + buf * 16384 + col * 64 +
                              ((l4 ^ ((col >> 1) & 3)) << 4));
    }

    __builtin_amdgcn_s_setprio(1);
    #pragma unroll
    for (int n = 0; n < NF; ++n)
      #pragma unroll
      for (int m = 0; m < MR; ++m)
        acc[m][n] = __builtin_amdgcn_mfma_f32_16x16x32_bf16(a[m], b[n], acc[m][n], 0, 0, 0);
    __builtin_amdgcn_s_setprio(0);
  }

  // all waves' A-reads complete (reads retire before their MFMAs, which
  // precede this barrier) -> in-place overwrite of the A region is safe
  __builtin_amdgcn_s_barrier();

  #pragma unroll
  for (int n = 0; n < NF; ++n) {
    int col = c0 + n * 16 + l15;
    float bv = bias[col];
    #pragma unroll
    for (int m = 0; m < MR; ++m) {
      #pragma unroll
      for (int j = 0; j < 4; ++j) {
        float v = acc[m][n][j] + bv;
        if (RELU) v = fmaxf(v, 0.f);
        int row = r0 + m * 16 + l4 * 4 + j;
        *(bf16*)(lds + swz(out_base, row, out_stride, col * 2)) = (bf16)v;
      }
    }
  }
  __syncthreads();  // full drain: epilogue visible to next layer
}

// ================= main fused kernel =================
__global__ __launch_bounds__(THREADS, 4) void k_main(
    const float* __restrict__ x, const int* __restrict__ ctrl, const int* __restrict__ perm,
    const bf16* __restrict__ wpack,
    const float* __restrict__ b0, const float* __restrict__ bs,
    const float* __restrict__ tb0p, const float* __restrict__ tbsp,
    const float* __restrict__ featb, const float* __restrict__ alphaW,
    const float* __restrict__ alphab, const float* __restrict__ viewsb,
    const float* __restrict__ rgbW, const float* __restrict__ rgbb,
    float* __restrict__ outp) {
  __shared__ __attribute__((aligned(16))) char lds[LDS_BYTES];
  __shared__ int pidx[TILE];
  __shared__ float alpha_s[TILE];

  const int tid = threadIdx.x;
  const int lane = tid & 63, wave = tid >> 6;

  // ---- resolve head + tile from control block ----
  const int tbA = ctrl[24], tbB = ctrl[25], tbC = ctrl[26], tbD = ctrl[27], tbE = ctrl[28];
  const int bid = blockIdx.x;
  if (bid >= tbE) return;
  const int hh = (bid >= tbB) + (bid >= tbC) + (bid >= tbD);
  const int tb_h = (hh == 0) ? tbA : ((hh == 1) ? tbB : ((hh == 2) ? tbC : tbD));
  const int start = ctrl[8 + hh] + (bid - tb_h) * TILE;
  const int nv = min(TILE, ctrl[8 + hh + 1] - start);

  if (tid < TILE) pidx[tid] = (tid < nv) ? perm[start + tid] : -1;
  __syncthreads();

  // ---- pts -> LDS bf16 [64][64] (col 63 = 0, rows>=nv = 0) ----
  for (int i = tid; i < TILE * 64; i += THREADS) {
    int row = i >> 6, c = i & 63;
    int p = pidx[row];
    float v = (p >= 0 && c < 63) ? x[p * 90 + c] : 0.f;
    *(bf16*)(lds + swz(PTS_BASE, row, 128, c * 2)) = (bf16)v;
  }
  __syncthreads();  // pts visible before W0's raw-barrier loop reads them

  const bf16* W0p    = wpack + OFF_W0;
  const bf16* Wsp    = wpack + OFF_WS;
  const bf16* tW0p   = wpack + OFF_TW0 + hh * 81920;
  const bf16* tWsp   = wpack + OFF_TWS + hh * 3 * 65536;
  const bf16* featWp = wpack + OFF_FEATW + hh * 65536;
  const bf16* viewsWp= wpack + OFF_VIEWSW + hh * 36864;

  // trunk: 63->256, 3x 256->256 (in-place H)
  mfma_layer<2, 4, true, 2, 0, 256>(lds, W0p, 64, b0, PTS_BASE, 128, 0, 0, H_BASE, 512, lane, wave);
  mfma_layer<2, 4, true, 8, 0, 256>(lds, Wsp,          256, bs,       H_BASE, 512, 0, 0, H_BASE, 512, lane, wave);
  mfma_layer<2, 4, true, 8, 0, 256>(lds, Wsp + 65536,  256, bs + 256, H_BASE, 512, 0, 0, H_BASE, 512, lane, wave);
  mfma_layer<2, 4, true, 8, 0, 256>(lds, Wsp + 131072, 256, bs + 512, H_BASE, 512, 0, 0, H_BASE, 512, lane, wave);
  // T0: concat(pts, h) 320 -> 256
  mfma_layer<2, 4, true, 2, 8, 256>(lds, tW0p, 320, tb0p + hh * 256,
                                    PTS_BASE, 128, H_BASE, 512, H_BASE, 512, lane, wave);

  // views -> PTS cols 0..31 (T0's PTS reads complete before its epilogue barrier)
  for (int i = tid; i < TILE * 32; i += THREADS) {
    int row = i >> 5, c = i & 31;
    int p = pidx[row];
    float v = (p >= 0 && c < 27) ? x[p * 90 + 63 + c] : 0.f;
    *(bf16*)(lds + swz(PTS_BASE, row, 128, c * 2)) = (bf16)v;
  }
  __syncthreads();  // views-gather writes drained before later raw-barrier layers

  // head layers
  mfma_layer<2, 4, true, 8, 0, 256>(lds, tWsp,          256, tbsp + hh * 768,       H_BASE, 512, 0, 0, H_BASE, 512, lane, wave);
  mfma_layer<2, 4, true, 8, 0, 256>(lds, tWsp + 65536,  256, tbsp + hh * 768 + 256, H_BASE, 512, 0, 0, H_BASE, 512, lane, wave);
  mfma_layer<2, 4, true, 8, 0, 256>(lds, tWsp + 131072, 256, tbsp + hh * 768 + 512, H_BASE, 512, 0, 0, H_BASE, 512, lane, wave);

  // ---- alpha = ha . alphaW[hh] + alphab (waves 0-3; completes before feat's
  //      epilogue because all waves must pass feat's kc barriers first) ----
  if (wave < 4) {
    int p = wave * 16 + (lane & 15);
    int kq = lane >> 4;
    const float* aW = alphaW + hh * 256;
    float s = 0.f;
    for (int i = 0; i < 8; ++i) {
      int k = kq * 64 + i * 8;
      bf16x8 hv8 = *(const bf16x8*)(lds + swz(H_BASE, p, 512, k * 2));
      #pragma unroll
      for (int j = 0; j < 8; ++j) s += (float)hv8[j] * aW[k + j];
    }
    s += __shfl_xor(s, 16);
    s += __shfl_xor(s, 32);
    if (kq == 0) alpha_s[p] = s + alphab[hh];
  }

  // feat: 256->256 in-place, NO relu
  mfma_layer<2, 4, false, 8, 0, 256>(lds, featWp, 256, featb + hh * 256,
                                     H_BASE, 512, 0, 0, H_BASE, 512, lane, wave);
  // views: concat(feat, views[32pad]) 288 -> 128, relu, into H cols 0..127
  mfma_layer<2, 2, true, 8, 1, 128>(lds, viewsWp, 288, viewsb + hh * 128,
                                    H_BASE, 512, PTS_BASE, 128, H_BASE, 512, lane, wave);

  // ---- rgb = hv . rgbW[hh] + rgbb ; write float4 {r,g,b,alpha} (waves 0-3) ----
  if (wave < 4) {
    int p = wave * 16 + (lane & 15);
    int kq = lane >> 4;
    const float* rW = rgbW + hh * 128 * 3;
    float r0 = 0.f, r1 = 0.f, r2 = 0.f;
    for (int i = 0; i < 4; ++i) {
      int k = kq * 32 + i * 8;
      bf16x8 hv8 = *(const bf16x8*)(lds + swz(H_BASE, p, 512, k * 2));
      #pragma unroll
      for (int j = 0; j < 8; ++j) {
        float hvf = (float)hv8[j];
        r0 += hvf * rW[(k + j) * 3 + 0];
        r1 += hvf * rW[(k + j) * 3 + 1];
        r2 += hvf * rW[(k + j) * 3 + 2];
      }
    }
    r0 += __shfl_xor(r0, 16); r0 += __shfl_xor(r0, 32);
    r1 += __shfl_xor(r1, 16); r1 += __shfl_xor(r1, 32);
    r2 += __shfl_xor(r2, 16); r2 += __shfl_xor(r2, 32);
    if (kq == 0 && p < nv) {
      int pt = pidx[p];
      float4 o = make_float4(r0 + rgbb[hh * 3 + 0], r1 + rgbb[hh * 3 + 1],
                             r2 + rgbb[hh * 3 + 2], alpha_s[p]);
      *(float4*)(outp + pt * 4) = o;
    }
  }
}

// ================= launch =================
extern "C" void kernel_launch(void* const* d_in, const int* in_sizes, int n_in,
                              void* d_out, int out_size, void* d_ws, size_t ws_size,
                              hipStream_t stream) {
  const float* x      = (const float*)d_in[0];
  const int*   head   = (const int*)d_in[1];
  const float* W0     = (const float*)d_in[2];
  const float* b0     = (const float*)d_in[3];
  const float* Ws     = (const float*)d_in[4];
  const float* bs     = (const float*)d_in[5];
  const float* tW0    = (const float*)d_in[6];
  const float* tb0    = (const float*)d_in[7];
  const float* tWs    = (const float*)d_in[8];
  const float* tbs    = (const float*)d_in[9];
  const float* featW  = (const float*)d_in[10];
  const float* featb  = (const float*)d_in[11];
  const float* alphaW = (const float*)d_in[12];
  const float* alphab = (const float*)d_in[13];
  const float* viewsW = (const float*)d_in[14];
  const float* viewsb = (const float*)d_in[15];
  const float* rgbW   = (const float*)d_in[16];
  const float* rgbb   = (const float*)d_in[17];

  int*  ctrl  = (int*)d_ws;
  int*  perm  = (int*)((char*)d_ws + WS_PERM_OFF);
  bf16* wpack = (bf16*)((char*)d_ws + WS_WPACK_OFF);

  hipMemsetAsync(ctrl, 0, 256, stream);
  k_pack<<<2048, 256, 0, stream>>>(W0, Ws, tW0, tWs, featW, viewsW, wpack, head, ctrl);
  k_scan<<<1, 1, 0, stream>>>(ctrl);
  k_scatter<<<N_PTS / 256, 256, 0, stream>>>(head, ctrl, perm);
  k_main<<<N_PTS / TILE + 4, THREADS, 0, stream>>>(x, ctrl, perm, wpack,
                                                   b0, bs, tb0, tbs, featb, alphaW, alphab,
                                                   viewsb, rgbW, rgbb, (float*)d_out);
}